// Round 2
// baseline (157.328 us; speedup 1.0000x reference)
//
#include <hip/hip_runtime.h>
#include <math.h>

// out[n,0,i,j] = (1/64) * sum_{c,p,q} w[c]*sqrt(z[n,c,p,q]) * sqrt(x[n,c,i+p,j+q])
//   N=16, C=256, k=8, m=63, mo=56.
//
// FUSED shift-GEMM (no workspace -> no 256 MiB harness re-poison fill, which was
// 41 us/iter and dominated round 1):
//   per (sample, 7-row output band, 64-channel chunk):
//     S[pq][pix] = sum_c (w*sqrt(z))[pq,c] * sqrt(x)[c,pix]   via mfma_16x16x32_bf16
//     each S element belongs to exactly ONE output: oacc[rt-p][s-q] += S  (LDS ds_add_f32)
//   then one global atomicAdd per output per channel chunk (out memset-zeroed).

#define NS 16
#define NC 256
#define PQ 64
#define MI 63
#define MO 56
#define NPIX (MI*MI)            // 3969
#define NOUT (MO*MO)            // 3136

#define IH 7                    // output rows per band
#define NBAND 8                 // 8*7 = 56 output rows
#define CSPLIT 4                // channel chunks
#define NCH (NC/CSPLIT)         // 64 channels per block
#define TROWS (IH + 7)          // 14 pixel rows per tile
#define TPIX (TROWS*MI)         // 882 pixels per tile (contiguous in memory!)
#define NGRP ((TPIX + 15)/16)   // 56 pixel groups -> 14 per wave
#define ZP (NCH + 8)            // zs row stride (shorts): pad to dodge bank alignment

typedef __attribute__((ext_vector_type(8))) short bf16x8;
typedef __attribute__((ext_vector_type(4))) float f32x4;

static __device__ __forceinline__ short f2bf(float f) {
    // round-to-nearest-even fp32 -> bf16 (inputs finite, nonnegative)
    union { float f; unsigned u; } v; v.f = f;
    return (short)((v.u + 0x7fffu + ((v.u >> 16) & 1u)) >> 16);
}

__global__ __launch_bounds__(256, 2)
void bhat_fused(const float* __restrict__ z, const float* __restrict__ x,
                const float* __restrict__ w, float* __restrict__ out) {
    __shared__ short zs[PQ * ZP];       // A = w*sqrt(z): zs[pq][c], 9.2 KB bf16
    __shared__ float oacc[IH * MO];     // band output accumulator, 1.57 KB

    const int n    = blockIdx.x;
    const int band = blockIdx.y;
    const int c0   = blockIdx.z * NCH;
    const int tid  = threadIdx.x;
    const int i0   = band * IH;

    for (int i = tid; i < IH * MO; i += 256) oacc[i] = 0.0f;

    // Stage A chunk: coalesced z reads (idx = c*64+pq), wave-uniform w[c].
    {
        const float* zb = z + ((size_t)n * NC + c0) * PQ;
        #pragma unroll
        for (int it = 0; it < (PQ * NCH) / 256; ++it) {
            int idx = it * 256 + tid;
            int c = idx >> 6, pq = idx & 63;
            zs[pq * ZP + c] = f2bf(w[c0 + c] * sqrtf(zb[(size_t)c * PQ + pq]));
        }
    }
    __syncthreads();

    const int wave = tid >> 6, lane = tid & 63;
    const int lm = lane & 15, lg = lane >> 4;

    // Band's pixel tile = rows i0..i0+13, all 63 cols -> CONTIGUOUS flat range.
    const float* xb = x + ((size_t)n * NC + c0) * NPIX + (size_t)i0 * MI;

    for (int g = wave; g < NGRP; g += 4) {
        const int pit  = g * 16 + lm;                    // tile-flat pixel
        const int pitc = pit > TPIX - 1 ? TPIX - 1 : pit; // clamp tail loads

        f32x4 acc[4];
        #pragma unroll
        for (int mt = 0; mt < 4; ++mt) acc[mt] = (f32x4){0.f, 0.f, 0.f, 0.f};

        #pragma unroll
        for (int kk = 0; kk < NCH / 32; ++kk) {
            const int cb = kk * 32 + lg * 8;             // this lane-group's channels
            bf16x8 bfrag;
            #pragma unroll
            for (int j = 0; j < 8; ++j)
                bfrag[j] = f2bf(sqrtf(xb[(size_t)(cb + j) * NPIX + pitc]));
            // A-frag: same intra-lane k-order as B-frag -> HW k-permutation cancels.
            #pragma unroll
            for (int mt = 0; mt < 4; ++mt) {
                const bf16x8 afrag = *(const bf16x8*)(&zs[(mt * 16 + lm) * ZP + cb]);
                acc[mt] = __builtin_amdgcn_mfma_f32_16x16x32_bf16(afrag, bfrag, acc[mt], 0, 0, 0);
            }
        }

        // Scatter: D layout (m89): pq = mt*16 + lg*4 + t, pixel col = lm.
        const int rt = pit / MI, s = pit - rt * MI;      // tile-local row, col
        const bool pv = pit < TPIX;
        #pragma unroll
        for (int mt = 0; mt < 4; ++mt)
            #pragma unroll
            for (int t = 0; t < 4; ++t) {
                const int pq = mt * 16 + lg * 4 + t;
                const int p = pq >> 3, q = pq & 7;
                const int oi = rt - p, j = s - q;
                if (pv && (unsigned)oi < IH && (unsigned)j < MO)
                    atomicAdd(&oacc[oi * MO + j], acc[mt][t]);
            }
    }

    __syncthreads();
    float* ob = out + (size_t)n * NOUT + (size_t)i0 * MO;
    for (int i = tid; i < IH * MO; i += 256)
        atomicAdd(&ob[i], oacc[i] * (1.0f / 64.0f));
}

extern "C" void kernel_launch(void* const* d_in, const int* in_sizes, int n_in,
                              void* d_out, int out_size, void* d_ws, size_t ws_size,
                              hipStream_t stream) {
    const float* z = (const float*)d_in[0];   // (16,256,8,8)
    const float* x = (const float*)d_in[1];   // (16,256,63,63)
    const float* w = (const float*)d_in[2];   // (1,256,1,1,1) -> 256 floats
    float* out = (float*)d_out;               // (16,1,56,56)

    // d_out is re-poisoned each iteration; channel-chunk blocks accumulate atomically.
    hipMemsetAsync(out, 0, (size_t)out_size * sizeof(float), stream);

    dim3 grid(NS, NBAND, CSPLIT);             // (16, 8, 4) = 512 blocks
    bhat_fused<<<grid, 256, 0, stream>>>(z, x, w, out);
}